// Round 4
// baseline (146.875 us; speedup 1.0000x reference)
//
#include <hip/hip_runtime.h>

#define A_DIM 5
#define B_DIM 32768
#define S_DIM 48
#define HID   256
#define LRELU 0.01f
#define BN_EPS 1e-5f

#define LDX 72    // xn LDS leading dim (bf16 elems)
#define LDE 264   // enc LDS leading dim

// ws float layout:
//   [0, 15360)      stats partials: 160 blocks x (48 sum + 48 sq)
//   [15360, 15840)  mean[240], rstd[240]
//   [15872, 16384)  sq_parts[512]
//   float 16384+ :  bf16 swizzled weights
#define OFF_ENC 0        // 2048 frags  (N=256, K=64 padded)
#define OFF_SEL 16384
#define OFF_KEY 81920
#define OFF_C1  147456
#define OFF_C2  212992

typedef __bf16 bf16x8 __attribute__((ext_vector_type(8)));
typedef float  f32x4  __attribute__((ext_vector_type(4)));

__device__ __forceinline__ unsigned short f2bf(float x) {
    unsigned u = __builtin_bit_cast(unsigned, x);
    unsigned r = (u + 0x7FFFu + ((u >> 16) & 1u)) >> 16;
    return (unsigned short)r;
}
__device__ __forceinline__ f32x4 mfma16(bf16x8 a, bf16x8 b, f32x4 c) {
    return __builtin_amdgcn_mfma_f32_16x16x32_bf16(a, b, c, 0, 0, 0);
}

// ---------------- Kernel A: BN partial sums (160 blocks x 256) ----------------
__global__ void stats1_kernel(const float* __restrict__ states, float* __restrict__ ws) {
    const int a = blockIdx.x >> 5;
    const int chunk = blockIdx.x & 31;
    const int t = threadIdx.x;
    const float* base = states + ((size_t)a * B_DIM + (size_t)chunk * 1024) * S_DIM;
    float s0 = 0.f, s1 = 0.f, s2 = 0.f, q0 = 0.f, q1 = 0.f, q2 = 0.f;
    for (int i = 0; i < 192; i += 3) {
        float x0 = base[t + (i + 0) * 256];
        float x1 = base[t + (i + 1) * 256];
        float x2 = base[t + (i + 2) * 256];
        s0 += x0; q0 += x0 * x0;
        s1 += x1; q1 += x1 * x1;
        s2 += x2; q2 += x2 * x2;
    }
    __shared__ float lsum[48], lsq[48];
    if (t < 48) { lsum[t] = 0.f; lsq[t] = 0.f; }
    __syncthreads();
    const int sA = t % 48, sB = (t + 16) % 48, sC = (t + 32) % 48;
    atomicAdd(&lsum[sA], s0); atomicAdd(&lsq[sA], q0);
    atomicAdd(&lsum[sB], s1); atomicAdd(&lsq[sB], q1);
    atomicAdd(&lsum[sC], s2); atomicAdd(&lsq[sC], q2);
    __syncthreads();
    if (t < 48) {
        ws[blockIdx.x * 96 + t] = lsum[t];
        ws[blockIdx.x * 96 + 48 + t] = lsq[t];
    }
}

// ---------------- Kernel B: finalize mean/rstd ----------------
__global__ void stats2_kernel(float* __restrict__ ws) {
    const int t = threadIdx.x;
    if (t >= 240) return;
    const int a = t / 48, s = t % 48;
    float sum = 0.f, sq = 0.f;
    for (int c = 0; c < 32; ++c) {
        sum += ws[(a * 32 + c) * 96 + s];
        sq  += ws[(a * 32 + c) * 96 + 48 + s];
    }
    const float mean = sum * (1.f / (float)B_DIM);
    const float var  = sq * (1.f / (float)B_DIM) - mean * mean;
    ws[15360 + t] = mean;
    ws[15600 + t] = rsqrtf(var + BN_EPS);
}

// ---------------- Kernel P: weights -> bf16 B-fragments ----------------
__global__ void prep_kernel(const float* __restrict__ W_enc, const float* __restrict__ W_key,
                            const float* __restrict__ W_sel, const float* __restrict__ W_c1,
                            const float* __restrict__ W_c2, unsigned short* __restrict__ wswz) {
    const int gid = blockIdx.x * 256 + threadIdx.x;
    float vals[8];
    unsigned short* dst;
    if (gid < 2048) {                       // W_enc: chunks=16, KS=2, K pad 48->64
        const int lid = gid, lane = lid & 63, fi = lid >> 6;
        const int ks = fi & 1, chunk = fi >> 1;
        const int n = (chunk << 4) + (lane & 15), k0 = ks * 32 + ((lane >> 4) << 3);
#pragma unroll
        for (int j = 0; j < 8; ++j) { int k = k0 + j; vals[j] = (k < 48) ? W_enc[k * 256 + n] : 0.f; }
        dst = wswz + OFF_ENC + (size_t)lid * 8;
    } else if (gid < 10240) {               // W_sel cat
        const int lid = gid - 2048, lane = lid & 63, fi = lid >> 6;
        const int ks = fi & 7, chunk = fi >> 3;
        const int n = (chunk << 4) + (lane & 15), k0 = ks * 32 + ((lane >> 4) << 3);
        const int head = n >> 6, d = n & 63;
#pragma unroll
        for (int j = 0; j < 8; ++j) { int k = k0 + j; vals[j] = W_sel[(head * 256 + k) * 64 + d]; }
        dst = wswz + OFF_SEL + (size_t)lid * 8;
    } else if (gid < 18432) {               // W_key cat
        const int lid = gid - 10240, lane = lid & 63, fi = lid >> 6;
        const int ks = fi & 7, chunk = fi >> 3;
        const int n = (chunk << 4) + (lane & 15), k0 = ks * 32 + ((lane >> 4) << 3);
        const int head = n >> 6, d = n & 63;
#pragma unroll
        for (int j = 0; j < 8; ++j) { int k = k0 + j; vals[j] = W_key[(head * 256 + k) * 64 + d]; }
        dst = wswz + OFF_KEY + (size_t)lid * 8;
    } else if (gid < 26624) {               // W_c1
        const int lid = gid - 18432, lane = lid & 63, fi = lid >> 6;
        const int ks = fi & 7, chunk = fi >> 3;
        const int n = (chunk << 4) + (lane & 15), k0 = ks * 32 + ((lane >> 4) << 3);
#pragma unroll
        for (int j = 0; j < 8; ++j) { int k = k0 + j; vals[j] = W_c1[k * 256 + n]; }
        dst = wswz + OFF_C1 + (size_t)lid * 8;
    } else if (gid < 27136) {               // W_c2: N pad 8->16
        const int lid = gid - 26624, lane = lid & 63, ks = lid >> 6;
        const int n = lane & 15, k0 = ks * 32 + ((lane >> 4) << 3);
#pragma unroll
        for (int j = 0; j < 8; ++j) { int k = k0 + j; vals[j] = (n < 8) ? W_c2[k * 8 + n] : 0.f; }
        dst = wswz + OFF_C2 + (size_t)lid * 8;
    } else return;
#pragma unroll
    for (int j = 0; j < 8; ++j) dst[j] = f2bf(vals[j]);
}

// K-loop with B-fragments loaded from global (L2/L3) — used for sel/c1
template<int KS>
__device__ __forceinline__ void gemm_block(const unsigned short* __restrict__ aL,
                                           const unsigned short* __restrict__ bW,
                                           int l15, int lg, int lane, int w,
                                           f32x4 acc[2][4]) {
#pragma unroll
    for (int ks = 0; ks < KS; ++ks) {
        bf16x8 af[4];
#pragma unroll
        for (int rb = 0; rb < 4; ++rb)
            af[rb] = *(const bf16x8*)(aL + (rb * 16 + l15) * LDE + ks * 32 + lg * 8);
#pragma unroll
        for (int c = 0; c < 2; ++c) {
            const int chunk = w * 2 + c;
            bf16x8 bf = *(const bf16x8*)(bW + ((size_t)(chunk * KS + ks) * 64 + lane) * 8);
#pragma unroll
            for (int rb = 0; rb < 4; ++rb)
                acc[c][rb] = mfma16(af[rb], bf, acc[c][rb]);
        }
    }
}

__device__ __forceinline__ void store_tile(unsigned short* __restrict__ dstL, int wn, int l15, int lg,
                                           const f32x4 acc[2][4], float bias0, float bias1, bool dolrelu) {
#pragma unroll
    for (int c = 0; c < 2; ++c) {
        const float bias = c ? bias1 : bias0;
        const int col = wn + c * 16 + l15;
#pragma unroll
        for (int rb = 0; rb < 4; ++rb)
#pragma unroll
            for (int r = 0; r < 4; ++r) {
                const int row = rb * 16 + lg * 4 + r;
                float v = acc[c][rb][r] + bias;
                if (dolrelu) v = v >= 0.f ? v : LRELU * v;
                dstL[row * LDE + col] = f2bf(v);
            }
    }
}

// ---------------- Kernel C: fused main (512 blocks x 512 threads) ----------------
__global__ void __launch_bounds__(512, 2)
main_kernel(const float* __restrict__ states,
            const float* __restrict__ b_enc, const float* __restrict__ b_c1,
            const float* __restrict__ b_c2,
            const unsigned short* __restrict__ wswz,
            const float* __restrict__ meanrstd,
            float* __restrict__ out, float* __restrict__ sq_parts)
{
    extern __shared__ char smem[];
    unsigned short* xnL  = (unsigned short*)smem;            // 64*72 bf16   @0
    unsigned short* encL = xnL + 64 * LDX;                   // 64*264 bf16  @9216
    float* pbuf = (float*)(encL + 64 * LDE);                 // 8*64 f32     @43008
    float* mrL  = pbuf + 8 * 64;                             // 480 f32
    float* redF = mrL + 480;                                 // 8 f32

    const int t    = threadIdx.x;
    const int lane = t & 63;
    const int w    = t >> 6;
    const int l15  = lane & 15;
    const int lg   = lane >> 4;
    const int b0   = blockIdx.x * 64;
    const int wn   = w * 32;

    const float benc0 = b_enc[wn + l15], benc1 = b_enc[wn + 16 + l15];
    const float bc10  = b_c1[wn + l15],  bc11  = b_c1[wn + 16 + l15];

    // hoisted W_enc (16 VGPR) and W_key (64 VGPR) B-fragments — persist all agents
    bf16x8 encB[2][2];
#pragma unroll
    for (int c = 0; c < 2; ++c)
#pragma unroll
        for (int ks = 0; ks < 2; ++ks)
            encB[c][ks] = *(const bf16x8*)(wswz + OFF_ENC +
                           ((size_t)((w * 2 + c) * 2 + ks) * 64 + lane) * 8);
    bf16x8 keyB[2][8];
#pragma unroll
    for (int c = 0; c < 2; ++c)
#pragma unroll
        for (int ks = 0; ks < 8; ++ks)
            keyB[c][ks] = *(const bf16x8*)(wswz + OFF_KEY +
                           ((size_t)((w * 2 + c) * 8 + ks) * 64 + lane) * 8);

    // prefetch agent 0 states (nt: don't pollute L2)
    float pf[6];
    {
        const float* sp = states + (size_t)b0 * S_DIM;
#pragma unroll
        for (int j = 0; j < 6; ++j) pf[j] = __builtin_nontemporal_load(sp + t + j * 512);
    }
    // mean/rstd -> LDS; zero xn K-pad cols 48..63
    if (t < 480) mrL[t] = meanrstd[t];
    for (int i = t; i < 64 * 16; i += 512)
        xnL[(i >> 4) * LDX + 48 + (i & 15)] = 0;
    __syncthreads();

    // write xn(0)
    {
        const float* mp = mrL, *rp = mrL + 240;
#pragma unroll
        for (int j = 0; j < 6; ++j) {
            const int i = t + j * 512, row = i / 48, s = i - row * 48;
            xnL[row * LDX + s] = f2bf((pf[j] - mp[s]) * rp[s]);
        }
    }
    __syncthreads();

    f32x4 selacc[2][4] = {};   // sel kept in registers (f32), layout == key acc layout
    float sqacc = 0.f;

    for (int a = 0; a < A_DIM; ++a) {
        // issue prefetch for next agent
        float pn[6];
        if (a < 4) {
            const float* sp = states + ((size_t)(a + 1) * B_DIM + b0) * S_DIM;
#pragma unroll
            for (int j = 0; j < 6; ++j) pn[j] = __builtin_nontemporal_load(sp + t + j * 512);
        }

        // ---- enc = leaky(xn @ W_enc + b_enc), B from registers ----
        {
            f32x4 acc[2][4] = {};
#pragma unroll
            for (int ks = 0; ks < 2; ++ks) {
                bf16x8 af[4];
#pragma unroll
                for (int rb = 0; rb < 4; ++rb)
                    af[rb] = *(const bf16x8*)(xnL + (rb * 16 + l15) * LDX + ks * 32 + lg * 8);
#pragma unroll
                for (int c = 0; c < 2; ++c)
#pragma unroll
                    for (int rb = 0; rb < 4; ++rb)
                        acc[c][rb] = mfma16(af[rb], encB[c][ks], acc[c][rb]);
            }
            // fold previous agent's logits^2 into this phase
            if (a >= 2 && t < 256) {
                const int row = t & 63, k = t >> 6;
                const float l = pbuf[(2 * k) * 64 + row] + pbuf[(2 * k + 1) * 64 + row];
                sqacc += l * l;
            }
            store_tile(encL, wn, l15, lg, acc, benc0, benc1, true);
        }
        __syncthreads();

        if (a == 0) {
            // sel = enc @ W_sel -> persistent registers (no LDS round-trip)
            gemm_block<8>(encL, wswz + OFF_SEL, l15, lg, lane, w, selacc);
            // h = leaky(enc @ W_c1 + b_c1)
            f32x4 acc3[2][4] = {};
            gemm_block<8>(encL, wswz + OFF_C1, l15, lg, lane, w, acc3);
            // write xn(1)
            {
                const float* mp = mrL + 48, *rp = mrL + 240 + 48;
#pragma unroll
                for (int j = 0; j < 6; ++j) {
                    const int i = t + j * 512, row = i / 48, s = i - row * 48;
                    xnL[row * LDX + s] = f2bf((pn[j] - mp[s]) * rp[s]);
                }
            }
            __syncthreads();
            store_tile(encL, wn, l15, lg, acc3, bc10, bc11, true);   // encL <- h
            __syncthreads();
            // all_q = h @ W_c2 + b_c2
            if (w < 4) {
                f32x4 q = {};
#pragma unroll
                for (int ks = 0; ks < 8; ++ks) {
                    bf16x8 af = *(const bf16x8*)(encL + (w * 16 + l15) * LDE + ks * 32 + lg * 8);
                    bf16x8 bf = *(const bf16x8*)(wswz + OFF_C2 + ((size_t)(ks * 64 + lane)) * 8);
                    q = mfma16(af, bf, q);
                }
                if (l15 < 8) {
                    const float bq = b_c2[l15];
#pragma unroll
                    for (int r = 0; r < 4; ++r) {
                        const int row = w * 16 + lg * 4 + r;
                        __builtin_nontemporal_store(q[r] + bq, &out[(size_t)(b0 + row) * 8 + l15]);
                    }
                }
            }
            __syncthreads();
        } else {
            // keys = enc @ W_key, B from registers; logits = <selacc, keyacc> elementwise
            f32x4 acc2[2][4] = {};
#pragma unroll
            for (int ks = 0; ks < 8; ++ks) {
                bf16x8 af[4];
#pragma unroll
                for (int rb = 0; rb < 4; ++rb)
                    af[rb] = *(const bf16x8*)(encL + (rb * 16 + l15) * LDE + ks * 32 + lg * 8);
#pragma unroll
                for (int c = 0; c < 2; ++c)
#pragma unroll
                    for (int rb = 0; rb < 4; ++rb)
                        acc2[c][rb] = mfma16(af[rb], keyB[c][ks], acc2[c][rb]);
            }
            float p[4][4];
#pragma unroll
            for (int rb = 0; rb < 4; ++rb)
#pragma unroll
                for (int r = 0; r < 4; ++r)
                    p[rb][r] = selacc[0][rb][r] * acc2[0][rb][r] + selacc[1][rb][r] * acc2[1][rb][r];
#pragma unroll
            for (int m = 1; m < 16; m <<= 1)
#pragma unroll
                for (int rb = 0; rb < 4; ++rb)
#pragma unroll
                    for (int r = 0; r < 4; ++r)
                        p[rb][r] += __shfl_xor(p[rb][r], m);
            if (l15 == 0) {
#pragma unroll
                for (int rb = 0; rb < 4; ++rb)
#pragma unroll
                    for (int r = 0; r < 4; ++r)
                        pbuf[w * 64 + rb * 16 + lg * 4 + r] = p[rb][r];
            }
            // write xn(a+1)
            if (a < 4) {
                const float* mp = mrL + (a + 1) * 48, *rp = mrL + 240 + (a + 1) * 48;
#pragma unroll
                for (int j = 0; j < 6; ++j) {
                    const int i = t + j * 512, row = i / 48, s = i - row * 48;
                    xnL[row * LDX + s] = f2bf((pn[j] - mp[s]) * rp[s]);
                }
            }
            __syncthreads();
        }
    }

    // last agent's logits^2
    if (t < 256) {
        const int row = t & 63, k = t >> 6;
        const float l = pbuf[(2 * k) * 64 + row] + pbuf[(2 * k + 1) * 64 + row];
        sqacc += l * l;
    }
    // wave reduce, then tiny cross-wave reduce
    float v = sqacc;
#pragma unroll
    for (int m = 1; m < 64; m <<= 1) v += __shfl_xor(v, m);
    if (lane == 0) redF[w] = v;
    __syncthreads();
    if (t == 0) {
        float s = 0.f;
#pragma unroll
        for (int i = 0; i < 8; ++i) s += redF[i];
        sq_parts[blockIdx.x] = s;
    }
}

// ---------------- Kernel D: final reg reduce ----------------
__global__ void reduce_reg_kernel(const float* __restrict__ sq_parts, float* __restrict__ out_reg) {
    __shared__ float red[256];
    const int t = threadIdx.x;
    red[t] = sq_parts[t] + sq_parts[t + 256];
    __syncthreads();
    for (int s = 128; s > 0; s >>= 1) {
        if (t < s) red[t] += red[t + s];
        __syncthreads();
    }
    if (t == 0) out_reg[0] = red[0] * (0.001f / ((float)B_DIM * 4.f));
}

extern "C" void kernel_launch(void* const* d_in, const int* in_sizes, int n_in,
                              void* d_out, int out_size, void* d_ws, size_t ws_size,
                              hipStream_t stream) {
    const float* states = (const float*)d_in[0];
    const float* W_enc  = (const float*)d_in[1];
    const float* b_enc  = (const float*)d_in[2];
    const float* W_key  = (const float*)d_in[3];
    const float* W_sel  = (const float*)d_in[4];
    // d_in[5]=W_val, d_in[6]=b_val: dead (multiplied by 0.0 in reference)
    const float* W_c1   = (const float*)d_in[7];
    const float* b_c1   = (const float*)d_in[8];
    const float* W_c2   = (const float*)d_in[9];
    const float* b_c2   = (const float*)d_in[10];
    float* out = (float*)d_out;
    float* ws  = (float*)d_ws;

    float* meanrstd = ws + 15360;
    float* sq_parts = ws + 15872;
    unsigned short* wswz = (unsigned short*)(ws + 16384);

    stats1_kernel<<<160, 256, 0, stream>>>(states, ws);
    stats2_kernel<<<1, 256, 0, stream>>>(ws);
    prep_kernel<<<106, 256, 0, stream>>>(W_enc, W_key, W_sel, W_c1, W_c2, wswz);

    const size_t ldsz = 64 * LDX * 2 + 64 * LDE * 2 + (8 * 64 + 480 + 8) * 4; // 47008 B
    main_kernel<<<512, 512, ldsz, stream>>>(states, b_enc, b_c1, b_c2, wswz,
                                            meanrstd, out, sq_parts);
    reduce_reg_kernel<<<1, 256, 0, stream>>>(sq_parts, out + (size_t)B_DIM * 8);
}